// Round 3
// baseline (1020.319 us; speedup 1.0000x reference)
//
#include <hip/hip_runtime.h>

// Problem constants
constexpr int Bb = 8, Ll = 2048, Ww = 1024;
constexpr int BL = Bb * Ll;              // 16384

typedef short bf16x8 __attribute__((ext_vector_type(8)));
typedef float f32x4  __attribute__((ext_vector_type(4)));

// ---------- bf16 helpers (RNE) ----------
__device__ inline unsigned short f2bf(float f) {
    union { float f; unsigned u; } v; v.f = f;
    unsigned u = v.u;
    unsigned r = (u + 0x7fffu + ((u >> 16) & 1u)) >> 16;
    return (unsigned short)r;
}
__device__ inline float bf2f(unsigned short h) {
    union { unsigned u; float f; } v; v.u = ((unsigned)h) << 16;
    return v.f;
}

// ---------- async global->LDS, 16B per lane ----------
__device__ inline void gl_lds16(const unsigned short* g, unsigned short* l) {
    __builtin_amdgcn_global_load_lds(
        (const __attribute__((address_space(1))) unsigned int*)g,
        (__attribute__((address_space(3))) unsigned int*)l, 16, 0, 0);
}

// ---------- kernel 0: mask dtype detect + expand to float (1=valid, 0=padded) ----------
__global__ void mask_expand_kernel(const void* __restrict__ mraw, float* __restrict__ maskf) {
    const unsigned char* mb = (const unsigned char*)mraw;
    const unsigned* mw = (const unsigned*)mraw;
    __shared__ int s_nonint, s_notf, s_hasf;
    if (threadIdx.x == 0) { s_nonint = 0; s_notf = 0; s_hasf = 0; }
    __syncthreads();
    int nonint = 0, notf = 0, hasf = 0;
    for (int i = threadIdx.x; i < BL; i += blockDim.x) {
        unsigned char c = mb[i];
        if ((i & 3) && c) nonint = 1;
    }
    for (int i = threadIdx.x; i < BL / 4; i += blockDim.x) {
        unsigned w = mw[i];
        if (w == 0x3f800000u) hasf = 1; else if (w) notf = 1;
    }
    if (nonint) atomicOr(&s_nonint, 1);
    if (notf)   atomicOr(&s_notf, 1);
    if (hasf)   atomicOr(&s_hasf, 1);
    __syncthreads();
    int is_f32  = (!s_notf) && s_hasf;
    int is_bool = (!is_f32) && s_nonint;
    for (int i = threadIdx.x; i < BL; i += blockDim.x) {
        int masked;
        if (is_bool) masked = (mb[i] != 0);
        else         masked = (mw[i] != 0u);
        maskf[i] = masked ? 0.0f : 1.0f;
    }
}

// ---------- kernel 1a: conv_w fp32 [g][o][c][k] -> pre-tiled swizzled bf16 images ----------
__global__ void wconv_kernel(const float* __restrict__ conv_w, unsigned short* __restrict__ w_t) {
    int gnt = blockIdx.x >> 2;           // 0..39 = g*20+nt
    int part = blockIdx.x & 3;
    int g = gnt / 20, nt = gnt % 20;
    int k = nt >> 2, o0 = (nt & 3) * 128;
    int tid = threadIdx.x;
    #pragma unroll
    for (int it = 0; it < 8; it++) {
        int chunk = part * 2048 + it * 256 + tid;    // 0..8191 per (g,nt)
        int r = chunk >> 6;                           // tile row
        int cq = chunk & 63;
        int cs = cq >> 2, q = cq & 3;
        int o = o0 + r;
        int c0 = cs * 32 + q * 8;                     // channel within group
        const float* src = conv_w + (((size_t)(g * 512 + o) * 512 + c0) * 5 + k);
        ushort4 lo, hi;
        lo.x = f2bf(src[0]);  lo.y = f2bf(src[5]);  lo.z = f2bf(src[10]); lo.w = f2bf(src[15]);
        hi.x = f2bf(src[20]); hi.y = f2bf(src[25]); hi.z = f2bf(src[30]); hi.w = f2bf(src[35]);
        int dst16 = (gnt * 16 + cs) * 512 + r * 4 + (q ^ (r & 3));
        *(ushort4*)&w_t[(size_t)dst16 * 8]     = lo;
        *(ushort4*)&w_t[(size_t)dst16 * 8 + 4] = hi;
    }
}

// ---------- kernel 1b: offsets (tanh(x@w_off)+pos -> idx/weights) + x -> tiled bf16 ----------
__global__ __launch_bounds__(256) void offsets_kernel(
    const float* __restrict__ x, const float* __restrict__ w_off, const float* __restrict__ b_off,
    unsigned short* __restrict__ x_t, int* __restrict__ idx0, int* __restrict__ idx1,
    float* __restrict__ w0a, float* __restrict__ w1a)
{
    int bl = blockIdx.x;
    int b = bl >> 11;
    int l = bl & (Ll - 1);
    int lt = l >> 7, r = l & 127;
    int tid = threadIdx.x;
    const float* xr = x + (size_t)bl * Ww;
    float4 v = *(const float4*)(xr + tid * 4);
    ushort4 xb4 = { f2bf(v.x), f2bf(v.y), f2bf(v.z), f2bf(v.w) };
    int cs = tid >> 3, q = (tid >> 1) & 3, half = tid & 1;
    int dst16 = ((b * 16 + lt) * 32 + cs) * 512 + r * 4 + (q ^ (r & 3));
    *(ushort4*)&x_t[(size_t)dst16 * 8 + half * 4] = xb4;

    float acc[5] = {0.f, 0.f, 0.f, 0.f, 0.f};
    int c = tid * 4;
    const float* vv = (const float*)&v;
    #pragma unroll
    for (int j = 0; j < 4; j++) {
        float xv = vv[j];
        #pragma unroll
        for (int k = 0; k < 5; k++) acc[k] += xv * w_off[(c + j) * 5 + k];
    }
    #pragma unroll
    for (int k = 0; k < 5; k++)
        for (int off = 32; off; off >>= 1) acc[k] += __shfl_down(acc[k], off);

    __shared__ float red[4][5];
    int wave = tid >> 6, lane = tid & 63;
    if (lane == 0) {
        #pragma unroll
        for (int k = 0; k < 5; k++) red[wave][k] = acc[k];
    }
    __syncthreads();
    if (tid < 5) {
        int k = tid;
        float s = red[0][k] + red[1][k] + red[2][k] + red[3][k] + b_off[k];
        float offv = tanhf(s) * 2.0f;
        float pos = (float)l + (float)(k - 2) + offv;
        float p0 = floorf(pos);
        float frac = pos - p0;
        int i0 = (int)p0;
        int i1 = i0 + 1;
        int v0 = (i0 >= 0) && (i0 < Ll);
        int v1 = (i1 >= 0) && (i1 < Ll);
        idx0[bl * 5 + k] = min(max(i0, 0), Ll - 1);
        idx1[bl * 5 + k] = min(max(i1, 0), Ll - 1);
        w0a[bl * 5 + k] = v0 ? (1.0f - frac) : 0.0f;
        w1a[bl * 5 + k] = v1 ? frac : 0.0f;
    }
}

// ---------- kernel 2: pure GEMM per batch: Z[k][l][w] = x_b @ W' (per group) ----------
__global__ __launch_bounds__(256) void gemm_kernel(
    const unsigned short* __restrict__ x_t, const unsigned short* __restrict__ w_t,
    unsigned short* __restrict__ Z, int b)
{
    __shared__ unsigned short As[8192];   // 2 images of 128x32 (16 KB)
    __shared__ unsigned short Bs[8192];
    const int tid = threadIdx.x;
    const int gx = blockIdx.x;            // g*20+nt
    const int mt = blockIdx.y;            // 0..15
    const int g = gx / 20, nt = gx % 20;
    const int lane = tid & 63, wave = tid >> 6;
    const int wr = (wave >> 1) * 64, wc = (wave & 1) * 64;
    const int l15 = lane & 15, l4 = lane >> 4;
    const int sw = (l4 ^ (l15 & 3)) * 8;  // swizzled chunk offset, in ushorts

    const unsigned short* Ab = x_t + ((size_t)((b * 16 + mt) * 32 + g * 16)) * 4096 + tid * 8;
    const unsigned short* Bp = w_t + ((size_t)gx * 16) * 4096 + tid * 8;

    f32x4 acc[4][4] = {};
    for (int ks = 0; ks < 8; ks++) {
        const unsigned short* ga = Ab + ks * 8192;
        const unsigned short* gb = Bp + ks * 8192;
        #pragma unroll
        for (int c = 0; c < 4; c++) {
            gl_lds16(ga + c * 2048, &As[tid * 8 + c * 2048]);
            gl_lds16(gb + c * 2048, &Bs[tid * 8 + c * 2048]);
        }
        __syncthreads();                   // drains vmcnt (DMA) for this tile
        bf16x8 af[2][4], bfr[2][4];
        #pragma unroll
        for (int kk = 0; kk < 2; kk++)
            #pragma unroll
            for (int i = 0; i < 4; i++) {
                af[kk][i]  = *(const bf16x8*)&As[kk * 4096 + (wr + i * 16 + l15) * 32 + sw];
                bfr[kk][i] = *(const bf16x8*)&Bs[kk * 4096 + (wc + i * 16 + l15) * 32 + sw];
            }
        #pragma unroll
        for (int kk = 0; kk < 2; kk++)
            #pragma unroll
            for (int i = 0; i < 4; i++)
                #pragma unroll
                for (int j = 0; j < 4; j++)
                    acc[i][j] = __builtin_amdgcn_mfma_f32_16x16x32_bf16(af[kk][i], bfr[kk][j], acc[i][j], 0, 0, 0);
        __syncthreads();                   // ds_reads done before next DMA overwrites
    }
    const int k = nt >> 2, o0 = (nt & 3) * 128;
    unsigned short* Zp = Z + ((size_t)k * Ll) * Ww + (g * 512 + o0);
    #pragma unroll
    for (int j = 0; j < 4; j++) {
        int col = wc + j * 16 + l15;
        #pragma unroll
        for (int i = 0; i < 4; i++) {
            int row0 = mt * 128 + wr + i * 16 + l4 * 4;
            #pragma unroll
            for (int rr = 0; rr < 4; rr++)
                Zp[(size_t)(row0 + rr) * Ww + col] = f2bf(acc[i][j][rr]);
        }
    }
}

// ---------- kernel 3: gather/lerp + bias + LayerNorm + mask + pooled partials ----------
// One block per 2 rows; all 20 Z-row loads issued before any use (MLP), one barrier pair.
__global__ __launch_bounds__(256) void gather_kernel(
    const unsigned short* __restrict__ Z, const int* __restrict__ idx0, const int* __restrict__ idx1,
    const float* __restrict__ w0a, const float* __restrict__ w1a, const float* __restrict__ conv_b,
    const float* __restrict__ gamma, const float* __restrict__ beta, const float* __restrict__ maskf,
    float* __restrict__ pooled, int b)
{
    const int tid = threadIdx.x;
    const int c = tid * 4;
    const int wave = tid >> 6, lane = tid & 63;
    const int l0 = blockIdx.x * 2;
    const int bl0 = b * Ll + l0;
    const float m0 = maskf[bl0], m1 = maskf[bl0 + 1];
    if (m0 == 0.0f && m1 == 0.0f) return;          // uniform across block

    // issue all 20 independent row loads up-front
    ushort4 z0[2][5], z1[2][5];
    float w0s[2][5], w1s[2][5];
    #pragma unroll
    for (int r = 0; r < 2; r++) {
        #pragma unroll
        for (int k = 0; k < 5; k++) {
            const int si = (bl0 + r) * 5 + k;
            const int i0 = idx0[si], i1 = idx1[si];
            w0s[r][k] = w0a[si]; w1s[r][k] = w1a[si];
            z0[r][k] = *(const ushort4*)(Z + ((size_t)k * Ll + i0) * Ww + c);
            z1[r][k] = *(const ushort4*)(Z + ((size_t)k * Ll + i1) * Ww + c);
        }
    }

    float cb[4], g4[4], be4[4];
    #pragma unroll
    for (int j = 0; j < 4; j++) { cb[j] = conv_b[c + j]; g4[j] = gamma[c + j]; be4[j] = beta[c + j]; }

    float h4[2][4];
    float s1[2], s2[2];
    #pragma unroll
    for (int r = 0; r < 2; r++) {
        #pragma unroll
        for (int j = 0; j < 4; j++) h4[r][j] = cb[j];
        #pragma unroll
        for (int k = 0; k < 5; k++) {
            const float w0 = w0s[r][k], w1 = w1s[r][k];
            h4[r][0] += w0 * bf2f(z0[r][k].x) + w1 * bf2f(z1[r][k].x);
            h4[r][1] += w0 * bf2f(z0[r][k].y) + w1 * bf2f(z1[r][k].y);
            h4[r][2] += w0 * bf2f(z0[r][k].z) + w1 * bf2f(z1[r][k].z);
            h4[r][3] += w0 * bf2f(z0[r][k].w) + w1 * bf2f(z1[r][k].w);
        }
        s1[r] = h4[r][0] + h4[r][1] + h4[r][2] + h4[r][3];
        s2[r] = h4[r][0]*h4[r][0] + h4[r][1]*h4[r][1] + h4[r][2]*h4[r][2] + h4[r][3]*h4[r][3];
    }
    #pragma unroll
    for (int r = 0; r < 2; r++)
        for (int off = 32; off; off >>= 1) {
            s1[r] += __shfl_down(s1[r], off);
            s2[r] += __shfl_down(s2[r], off);
        }
    __shared__ float red[4][4];
    if (lane == 0) { red[wave][0] = s1[0]; red[wave][1] = s2[0]; red[wave][2] = s1[1]; red[wave][3] = s2[1]; }
    __syncthreads();
    float S[4];
    #pragma unroll
    for (int j = 0; j < 4; j++) S[j] = red[0][j] + red[1][j] + red[2][j] + red[3][j];

    float pacc[4] = {0.f, 0.f, 0.f, 0.f};
    const float mm[2] = {m0, m1};
    #pragma unroll
    for (int r = 0; r < 2; r++) {
        float mu = S[r * 2] * (1.0f / 1024.0f);
        float var = S[r * 2 + 1] * (1.0f / 1024.0f) - mu * mu;
        float rstd = rsqrtf(var + 1e-5f) * mm[r];
        #pragma unroll
        for (int j = 0; j < 4; j++) pacc[j] += (h4[r][j] - mu) * rstd * g4[j] + be4[j] * mm[r];
    }
    #pragma unroll
    for (int j = 0; j < 4; j++) atomicAdd(&pooled[b * Ww + c + j], pacc[j]);
}

// ---------- kernel 4: lengths + projection ----------
__global__ void final_kernel(const float* __restrict__ pooled, const float* __restrict__ maskf,
                             const float* __restrict__ proj_w, const float* __restrict__ proj_b,
                             float* __restrict__ out)
{
    int b = blockIdx.x;
    int tid = threadIdx.x;
    float len = 0.f, dot = 0.f;
    for (int l = tid; l < Ll; l += 256) len += maskf[b * Ll + l];
    for (int c = tid; c < Ww; c += 256) dot += pooled[b * Ww + c] * proj_w[c];
    for (int off = 32; off; off >>= 1) {
        len += __shfl_down(len, off);
        dot += __shfl_down(dot, off);
    }
    __shared__ float rl[4], rd[4];
    int wave = tid >> 6, lane = tid & 63;
    if (lane == 0) { rl[wave] = len; rd[wave] = dot; }
    __syncthreads();
    if (tid == 0) {
        float Lt = rl[0] + rl[1] + rl[2] + rl[3];
        float Dt = rd[0] + rd[1] + rd[2] + rd[3];
        out[b] = Dt / fmaxf(Lt, 1.0f) + proj_b[0];
    }
}

// ---------- workspace layout (bytes, 16B-aligned) ----------
// maskf  @        0  (65536)
// pooled @    65536  (32768)
// idx0   @    98304  (327680)
// idx1   @   425984  (327680)
// w0a    @   753664  (327680)
// w1a    @  1081344  (327680)
// w_t    @  1409024  (5242880)    640 images x 8KB
// x_t    @  6651904  (33554432)   4096 images x 8KB
// Z      @ 40206336  (20971520)   [5][2048][1024] bf16, reused per batch
// total 61,177,856 B

extern "C" void kernel_launch(void* const* d_in, const int* in_sizes, int n_in,
                              void* d_out, int out_size, void* d_ws, size_t ws_size,
                              hipStream_t stream)
{
    const float* x      = (const float*)d_in[0];
    const void*  mask   = d_in[1];
    const float* w_off  = (const float*)d_in[2];
    const float* b_off  = (const float*)d_in[3];
    const float* conv_w = (const float*)d_in[4];
    const float* conv_b = (const float*)d_in[5];
    const float* gamma  = (const float*)d_in[6];
    const float* beta   = (const float*)d_in[7];
    const float* proj_w = (const float*)d_in[8];
    const float* proj_b = (const float*)d_in[9];
    float* out = (float*)d_out;

    char* ws = (char*)d_ws;
    float* maskf         = (float*)(ws + 0);
    float* pooled        = (float*)(ws + 65536);
    int*   idx0          = (int*)(ws + 98304);
    int*   idx1          = (int*)(ws + 425984);
    float* w0a           = (float*)(ws + 753664);
    float* w1a           = (float*)(ws + 1081344);
    unsigned short* w_t  = (unsigned short*)(ws + 1409024);
    unsigned short* x_t  = (unsigned short*)(ws + 6651904);
    unsigned short* Z    = (unsigned short*)(ws + 40206336);

    hipMemsetAsync(pooled, 0, Bb * Ww * sizeof(float), stream);
    mask_expand_kernel<<<1, 256, 0, stream>>>(mask, maskf);
    wconv_kernel<<<160, 256, 0, stream>>>(conv_w, w_t);
    offsets_kernel<<<BL, 256, 0, stream>>>(x, w_off, b_off, x_t, idx0, idx1, w0a, w1a);
    for (int b = 0; b < Bb; b++) {
        gemm_kernel<<<dim3(40, 16), 256, 0, stream>>>(x_t, w_t, Z, b);
        gather_kernel<<<1024, 256, 0, stream>>>(Z, idx0, idx1, w0a, w1a, conv_b,
                                                gamma, beta, maskf, pooled, b);
    }
    final_kernel<<<8, 256, 0, stream>>>(pooled, maskf, proj_w, proj_b, out);
}

// Round 4
// 382.596 us; speedup vs baseline: 2.6668x; 2.6668x over previous
//
#include <hip/hip_runtime.h>

// Problem constants
constexpr int Bb = 8, Ll = 2048, Ww = 1024;
constexpr int BL = Bb * Ll;              // 16384

typedef short bf16x8 __attribute__((ext_vector_type(8)));
typedef float f32x4  __attribute__((ext_vector_type(4)));

// ---------- bf16 helpers (RNE) ----------
__device__ inline unsigned short f2bf(float f) {
    union { float f; unsigned u; } v; v.f = f;
    unsigned u = v.u;
    unsigned r = (u + 0x7fffu + ((u >> 16) & 1u)) >> 16;
    return (unsigned short)r;
}
__device__ inline float bf2f(unsigned short h) {
    union { unsigned u; float f; } v; v.u = ((unsigned)h) << 16;
    return v.f;
}

// ---------- async global->LDS, 16B per lane ----------
__device__ inline void gl_lds16(const unsigned short* g, unsigned short* l) {
    __builtin_amdgcn_global_load_lds(
        (const __attribute__((address_space(1))) unsigned int*)g,
        (__attribute__((address_space(3))) unsigned int*)l, 16, 0, 0);
}

// ---------- kernel 0: mask dtype detect + expand to float (1=valid, 0=padded) ----------
__global__ void mask_expand_kernel(const void* __restrict__ mraw, float* __restrict__ maskf) {
    const unsigned char* mb = (const unsigned char*)mraw;
    const unsigned* mw = (const unsigned*)mraw;
    __shared__ int s_nonint, s_notf, s_hasf;
    if (threadIdx.x == 0) { s_nonint = 0; s_notf = 0; s_hasf = 0; }
    __syncthreads();
    int nonint = 0, notf = 0, hasf = 0;
    for (int i = threadIdx.x; i < BL; i += blockDim.x) {
        unsigned char c = mb[i];
        if ((i & 3) && c) nonint = 1;
    }
    for (int i = threadIdx.x; i < BL / 4; i += blockDim.x) {
        unsigned w = mw[i];
        if (w == 0x3f800000u) hasf = 1; else if (w) notf = 1;
    }
    if (nonint) atomicOr(&s_nonint, 1);
    if (notf)   atomicOr(&s_notf, 1);
    if (hasf)   atomicOr(&s_hasf, 1);
    __syncthreads();
    int is_f32  = (!s_notf) && s_hasf;
    int is_bool = (!is_f32) && s_nonint;
    for (int i = threadIdx.x; i < BL; i += blockDim.x) {
        int masked;
        if (is_bool) masked = (mb[i] != 0);
        else         masked = (mw[i] != 0u);
        maskf[i] = masked ? 0.0f : 1.0f;
    }
}

// ---------- kernel 1a: conv_w fp32 [g][o][c][k] -> pre-tiled swizzled bf16 images ----------
__global__ void wconv_kernel(const float* __restrict__ conv_w, unsigned short* __restrict__ w_t) {
    int gnt = blockIdx.x >> 2;           // 0..39 = g*20+nt
    int part = blockIdx.x & 3;
    int g = gnt / 20, nt = gnt % 20;
    int k = nt >> 2, o0 = (nt & 3) * 128;
    int tid = threadIdx.x;
    #pragma unroll
    for (int it = 0; it < 8; it++) {
        int chunk = part * 2048 + it * 256 + tid;    // 0..8191 per (g,nt)
        int r = chunk >> 6;                           // tile row
        int cq = chunk & 63;
        int cs = cq >> 2, q = cq & 3;
        int o = o0 + r;
        int c0 = cs * 32 + q * 8;                     // channel within group
        const float* src = conv_w + (((size_t)(g * 512 + o) * 512 + c0) * 5 + k);
        ushort4 lo, hi;
        lo.x = f2bf(src[0]);  lo.y = f2bf(src[5]);  lo.z = f2bf(src[10]); lo.w = f2bf(src[15]);
        hi.x = f2bf(src[20]); hi.y = f2bf(src[25]); hi.z = f2bf(src[30]); hi.w = f2bf(src[35]);
        int dst16 = (gnt * 16 + cs) * 512 + r * 4 + (q ^ (r & 3));
        *(ushort4*)&w_t[(size_t)dst16 * 8]     = lo;
        *(ushort4*)&w_t[(size_t)dst16 * 8 + 4] = hi;
    }
}

// ---------- kernel 1b: offsets (tanh(x@w_off)+pos -> idx/weights) + x -> tiled bf16 ----------
__global__ __launch_bounds__(256) void offsets_kernel(
    const float* __restrict__ x, const float* __restrict__ w_off, const float* __restrict__ b_off,
    unsigned short* __restrict__ x_t, int* __restrict__ idx0, int* __restrict__ idx1,
    float* __restrict__ w0a, float* __restrict__ w1a)
{
    int bl = blockIdx.x;
    int b = bl >> 11;
    int l = bl & (Ll - 1);
    int lt = l >> 7, r = l & 127;
    int tid = threadIdx.x;
    const float* xr = x + (size_t)bl * Ww;
    float4 v = *(const float4*)(xr + tid * 4);
    ushort4 xb4 = { f2bf(v.x), f2bf(v.y), f2bf(v.z), f2bf(v.w) };
    int cs = tid >> 3, q = (tid >> 1) & 3, half = tid & 1;
    int dst16 = ((b * 16 + lt) * 32 + cs) * 512 + r * 4 + (q ^ (r & 3));
    *(ushort4*)&x_t[(size_t)dst16 * 8 + half * 4] = xb4;

    float acc[5] = {0.f, 0.f, 0.f, 0.f, 0.f};
    int c = tid * 4;
    const float* vv = (const float*)&v;
    #pragma unroll
    for (int j = 0; j < 4; j++) {
        float xv = vv[j];
        #pragma unroll
        for (int k = 0; k < 5; k++) acc[k] += xv * w_off[(c + j) * 5 + k];
    }
    #pragma unroll
    for (int k = 0; k < 5; k++)
        for (int off = 32; off; off >>= 1) acc[k] += __shfl_down(acc[k], off);

    __shared__ float red[4][5];
    int wave = tid >> 6, lane = tid & 63;
    if (lane == 0) {
        #pragma unroll
        for (int k = 0; k < 5; k++) red[wave][k] = acc[k];
    }
    __syncthreads();
    if (tid < 5) {
        int k = tid;
        float s = red[0][k] + red[1][k] + red[2][k] + red[3][k] + b_off[k];
        float offv = tanhf(s) * 2.0f;
        float pos = (float)l + (float)(k - 2) + offv;
        float p0 = floorf(pos);
        float frac = pos - p0;
        int i0 = (int)p0;
        int i1 = i0 + 1;
        int v0 = (i0 >= 0) && (i0 < Ll);
        int v1 = (i1 >= 0) && (i1 < Ll);
        idx0[bl * 5 + k] = min(max(i0, 0), Ll - 1);
        idx1[bl * 5 + k] = min(max(i1, 0), Ll - 1);
        w0a[bl * 5 + k] = v0 ? (1.0f - frac) : 0.0f;
        w1a[bl * 5 + k] = v1 ? frac : 0.0f;
    }
}

// ---------- kernel 2: GEMM: Z[row][k][w] = x_b @ W' (per group), grid.z = batch ----------
__global__ __launch_bounds__(256) void gemm_kernel(
    const unsigned short* __restrict__ x_t, const unsigned short* __restrict__ w_t,
    unsigned short* __restrict__ Z, int b0, int zbase)
{
    __shared__ unsigned short As[8192];   // 2 images of 128x32 (16 KB)
    __shared__ unsigned short Bs[8192];
    const int tid = threadIdx.x;
    const int gx = blockIdx.x;            // g*20+nt
    const int mt = blockIdx.y;            // 0..15
    const int b = b0 + blockIdx.z;
    const int g = gx / 20, nt = gx % 20;
    const int lane = tid & 63, wave = tid >> 6;
    const int wr = (wave >> 1) * 64, wc = (wave & 1) * 64;
    const int l15 = lane & 15, l4 = lane >> 4;
    const int sw = (l4 ^ (l15 & 3)) * 8;  // swizzled chunk offset, in ushorts

    const unsigned short* Ab = x_t + ((size_t)((b * 16 + mt) * 32 + g * 16)) * 4096 + tid * 8;
    const unsigned short* Bp = w_t + ((size_t)gx * 16) * 4096 + tid * 8;

    f32x4 acc[4][4] = {};
    for (int ks = 0; ks < 8; ks++) {
        const unsigned short* ga = Ab + ks * 8192;
        const unsigned short* gb = Bp + ks * 8192;
        #pragma unroll
        for (int c = 0; c < 4; c++) {
            gl_lds16(ga + c * 2048, &As[tid * 8 + c * 2048]);
            gl_lds16(gb + c * 2048, &Bs[tid * 8 + c * 2048]);
        }
        __syncthreads();                   // drains vmcnt (DMA) for this tile
        bf16x8 af[2][4], bfr[2][4];
        #pragma unroll
        for (int kk = 0; kk < 2; kk++)
            #pragma unroll
            for (int i = 0; i < 4; i++) {
                af[kk][i]  = *(const bf16x8*)&As[kk * 4096 + (wr + i * 16 + l15) * 32 + sw];
                bfr[kk][i] = *(const bf16x8*)&Bs[kk * 4096 + (wc + i * 16 + l15) * 32 + sw];
            }
        #pragma unroll
        for (int kk = 0; kk < 2; kk++)
            #pragma unroll
            for (int i = 0; i < 4; i++)
                #pragma unroll
                for (int j = 0; j < 4; j++)
                    acc[i][j] = __builtin_amdgcn_mfma_f32_16x16x32_bf16(af[kk][i], bfr[kk][j], acc[i][j], 0, 0, 0);
        __syncthreads();                   // ds_reads done before next DMA overwrites
    }
    // epilogue: Z layout [row][k][w] (row local to Z buffer), w = g*512 + o
    const int k = nt >> 2, o0 = (nt & 3) * 128;
    const size_t zrow0 = (size_t)(b - zbase) * Ll;
    const int gc0 = g * 512 + o0;
    #pragma unroll
    for (int j = 0; j < 4; j++) {
        int col = gc0 + wc + j * 16 + l15;
        #pragma unroll
        for (int i = 0; i < 4; i++) {
            int row0 = mt * 128 + wr + i * 16 + l4 * 4;
            #pragma unroll
            for (int rr = 0; rr < 4; rr++)
                Z[((zrow0 + row0 + rr) * 5 + k) * 1024 + col] = f2bf(acc[i][j][rr]);
        }
    }
}

// ---------- kernel 3: gather/lerp + bias + LayerNorm + mask + pooled partials ----------
// One wave per 4 rows, lane owns 16 channels; Z layout [row][k][w] gives a +-5 row
// sliding window; XCD swizzle keeps each XCD on a contiguous l-range for L2 reuse.
__global__ __launch_bounds__(256, 4) void gather_kernel(
    const unsigned short* __restrict__ Z, const int* __restrict__ idx0, const int* __restrict__ idx1,
    const float* __restrict__ w0a, const float* __restrict__ w1a, const float* __restrict__ conv_b,
    const float* __restrict__ gamma, const float* __restrict__ maskf,
    float* __restrict__ pooled, int b0, int zbase)
{
    const int ngrpx = gridDim.x;                     // 128 row-groups per batch
    const int nb = ngrpx * gridDim.z;
    const int nper = nb >> 3;                        // blocks per XCD slice
    int v = blockIdx.x + ngrpx * blockIdx.z;
    int vr = (v & 7) * nper + (v >> 3);              // XCD-contiguous remap
    const int bz = vr / ngrpx;
    const int rg = vr % ngrpx;
    const int b = b0 + bz;
    const size_t zrow0 = (size_t)(b - zbase) * Ll;

    const int tid = threadIdx.x;
    const int wave = tid >> 6, lane = tid & 63;
    const int c0 = lane * 16;

    float pacc[16];
    #pragma unroll
    for (int j = 0; j < 16; j++) pacc[j] = 0.f;

    for (int r = 0; r < 4; r++) {
        const int l = rg * 16 + wave * 4 + r;
        const int bl = b * Ll + l;
        if (maskf[bl] == 0.0f) continue;             // wave-uniform
        float h[16];
        #pragma unroll
        for (int j = 0; j < 4; j++) {
            float4 cb = *(const float4*)(conv_b + c0 + j * 4);
            h[j*4+0] = cb.x; h[j*4+1] = cb.y; h[j*4+2] = cb.z; h[j*4+3] = cb.w;
        }
        for (int k = 0; k < 5; k++) {
            const int si = bl * 5 + k;
            const int i0 = idx0[si], i1 = idx1[si];
            const float w0 = w0a[si], w1 = w1a[si];
            const ushort4* p0 = (const ushort4*)(Z + ((zrow0 + i0) * 5 + k) * 1024 + c0);
            const ushort4* p1 = (const ushort4*)(Z + ((zrow0 + i1) * 5 + k) * 1024 + c0);
            ushort4 a0 = p0[0], a1 = p0[1], a2 = p0[2], a3 = p0[3];
            ushort4 e0 = p1[0], e1 = p1[1], e2 = p1[2], e3 = p1[3];
            h[0]  += w0 * bf2f(a0.x) + w1 * bf2f(e0.x);
            h[1]  += w0 * bf2f(a0.y) + w1 * bf2f(e0.y);
            h[2]  += w0 * bf2f(a0.z) + w1 * bf2f(e0.z);
            h[3]  += w0 * bf2f(a0.w) + w1 * bf2f(e0.w);
            h[4]  += w0 * bf2f(a1.x) + w1 * bf2f(e1.x);
            h[5]  += w0 * bf2f(a1.y) + w1 * bf2f(e1.y);
            h[6]  += w0 * bf2f(a1.z) + w1 * bf2f(e1.z);
            h[7]  += w0 * bf2f(a1.w) + w1 * bf2f(e1.w);
            h[8]  += w0 * bf2f(a2.x) + w1 * bf2f(e2.x);
            h[9]  += w0 * bf2f(a2.y) + w1 * bf2f(e2.y);
            h[10] += w0 * bf2f(a2.z) + w1 * bf2f(e2.z);
            h[11] += w0 * bf2f(a2.w) + w1 * bf2f(e2.w);
            h[12] += w0 * bf2f(a3.x) + w1 * bf2f(e3.x);
            h[13] += w0 * bf2f(a3.y) + w1 * bf2f(e3.y);
            h[14] += w0 * bf2f(a3.z) + w1 * bf2f(e3.z);
            h[15] += w0 * bf2f(a3.w) + w1 * bf2f(e3.w);
        }
        float s1 = 0.f, s2 = 0.f;
        #pragma unroll
        for (int j = 0; j < 16; j++) { s1 += h[j]; s2 += h[j] * h[j]; }
        #pragma unroll
        for (int off = 32; off; off >>= 1) {
            s1 += __shfl_xor(s1, off);
            s2 += __shfl_xor(s2, off);
        }
        const float mu = s1 * (1.0f / 1024.0f);
        const float var = s2 * (1.0f / 1024.0f) - mu * mu;
        const float rstd = rsqrtf(var + 1e-5f);
        #pragma unroll
        for (int j = 0; j < 4; j++) {
            float4 g4 = *(const float4*)(gamma + c0 + j * 4);
            pacc[j*4+0] += (h[j*4+0] - mu) * rstd * g4.x;
            pacc[j*4+1] += (h[j*4+1] - mu) * rstd * g4.y;
            pacc[j*4+2] += (h[j*4+2] - mu) * rstd * g4.z;
            pacc[j*4+3] += (h[j*4+3] - mu) * rstd * g4.w;
        }
    }
    // block merge (beta folded into final_kernel)
    __shared__ float spool[4][1024];
    #pragma unroll
    for (int j = 0; j < 4; j++)
        *(float4*)&spool[wave][c0 + j * 4] = *(float4*)&pacc[j * 4];
    __syncthreads();
    #pragma unroll
    for (int j = 0; j < 1; j++) {
        int ch = tid * 4;
        float4 a = *(float4*)&spool[0][ch];
        float4 bq = *(float4*)&spool[1][ch];
        float4 cq = *(float4*)&spool[2][ch];
        float4 dq = *(float4*)&spool[3][ch];
        atomicAdd(&pooled[b * Ww + ch + 0], a.x + bq.x + cq.x + dq.x);
        atomicAdd(&pooled[b * Ww + ch + 1], a.y + bq.y + cq.y + dq.y);
        atomicAdd(&pooled[b * Ww + ch + 2], a.z + bq.z + cq.z + dq.z);
        atomicAdd(&pooled[b * Ww + ch + 3], a.w + bq.w + cq.w + dq.w);
    }
}

// ---------- kernel 4: lengths + projection (beta folded in: + sum(beta*proj)) ----------
__global__ void final_kernel(const float* __restrict__ pooled, const float* __restrict__ maskf,
                             const float* __restrict__ beta, const float* __restrict__ proj_w,
                             const float* __restrict__ proj_b, float* __restrict__ out)
{
    int b = blockIdx.x;
    int tid = threadIdx.x;
    float len = 0.f, dotP = 0.f, dotB = 0.f;
    for (int l = tid; l < Ll; l += 256) len += maskf[b * Ll + l];
    for (int c = tid; c < Ww; c += 256) {
        dotP += pooled[b * Ww + c] * proj_w[c];
        dotB += beta[c] * proj_w[c];
    }
    for (int off = 32; off; off >>= 1) {
        len += __shfl_down(len, off);
        dotP += __shfl_down(dotP, off);
        dotB += __shfl_down(dotB, off);
    }
    __shared__ float rl[4], rp[4], rb[4];
    int wave = tid >> 6, lane = tid & 63;
    if (lane == 0) { rl[wave] = len; rp[wave] = dotP; rb[wave] = dotB; }
    __syncthreads();
    if (tid == 0) {
        float Lt = rl[0] + rl[1] + rl[2] + rl[3];
        float Pt = rp[0] + rp[1] + rp[2] + rp[3];
        float Bt = rb[0] + rb[1] + rb[2] + rb[3];
        out[b] = Pt / fmaxf(Lt, 1.0f) + Bt + proj_b[0];
    }
}

// ---------- workspace layout (bytes, 16B-aligned) ----------
// maskf  @        0  (65536)
// pooled @    65536  (32768)
// idx0   @    98304  (327680)
// idx1   @   425984  (327680)
// w0a    @   753664  (327680)
// w1a    @  1081344  (327680)
// w_t    @  1409024  (5242880)     640 images x 8KB
// x_t    @  6651904  (33554432)    4096 images x 8KB
// Z      @ 40206336  full: 167772160 ([16384][5][1024] bf16)  -> 207,978,496 total
//                    fallback: 20971520 (one batch)           ->  61,177,856 total

constexpr size_t Z_OFF = 40206336;
constexpr size_t FULL_TOTAL = Z_OFF + (size_t)BL * 5 * 1024 * 2;

extern "C" void kernel_launch(void* const* d_in, const int* in_sizes, int n_in,
                              void* d_out, int out_size, void* d_ws, size_t ws_size,
                              hipStream_t stream)
{
    const float* x      = (const float*)d_in[0];
    const void*  mask   = d_in[1];
    const float* w_off  = (const float*)d_in[2];
    const float* b_off  = (const float*)d_in[3];
    const float* conv_w = (const float*)d_in[4];
    const float* conv_b = (const float*)d_in[5];
    const float* gamma  = (const float*)d_in[6];
    const float* beta   = (const float*)d_in[7];
    const float* proj_w = (const float*)d_in[8];
    const float* proj_b = (const float*)d_in[9];
    float* out = (float*)d_out;

    char* ws = (char*)d_ws;
    float* maskf         = (float*)(ws + 0);
    float* pooled        = (float*)(ws + 65536);
    int*   idx0          = (int*)(ws + 98304);
    int*   idx1          = (int*)(ws + 425984);
    float* w0a           = (float*)(ws + 753664);
    float* w1a           = (float*)(ws + 1081344);
    unsigned short* w_t  = (unsigned short*)(ws + 1409024);
    unsigned short* x_t  = (unsigned short*)(ws + 6651904);
    unsigned short* Z    = (unsigned short*)(ws + Z_OFF);

    hipMemsetAsync(pooled, 0, Bb * Ww * sizeof(float), stream);
    mask_expand_kernel<<<1, 256, 0, stream>>>(mask, maskf);
    wconv_kernel<<<160, 256, 0, stream>>>(conv_w, w_t);
    offsets_kernel<<<BL, 256, 0, stream>>>(x, w_off, b_off, x_t, idx0, idx1, w0a, w1a);
    if (ws_size >= FULL_TOTAL) {
        gemm_kernel<<<dim3(40, 16, 8), 256, 0, stream>>>(x_t, w_t, Z, 0, 0);
        gather_kernel<<<dim3(128, 1, 8), 256, 0, stream>>>(Z, idx0, idx1, w0a, w1a, conv_b,
                                                           gamma, maskf, pooled, 0, 0);
    } else {
        for (int b = 0; b < Bb; b++) {
            gemm_kernel<<<dim3(40, 16, 1), 256, 0, stream>>>(x_t, w_t, Z, b, b);
            gather_kernel<<<dim3(128, 1, 1), 256, 0, stream>>>(Z, idx0, idx1, w0a, w1a, conv_b,
                                                               gamma, maskf, pooled, b, b);
        }
    }
    final_kernel<<<8, 256, 0, stream>>>(pooled, maskf, beta, proj_w, proj_b, out);
}